// Round 1
// baseline (2711.156 us; speedup 1.0000x reference)
//
#include <hip/hip_runtime.h>
#include <stdint.h>

#define DET_THRESH 0.015f

// =====================================================================
// Fused conv0(1->64,3x3)+bias+relu -> conv1(64->64,3x3)+bias+relu -> 2x2 maxpool
// in : (8,1,240,320)   out: (8,64,120,160)
// Tile: 16x16 output px, 16 co per block. 256 threads: c4(0..3) x p64 quad(2x2).
// =====================================================================
__global__ __launch_bounds__(256) void k_fused01(
    const float* __restrict__ x, const float* __restrict__ w0g, const float* __restrict__ b0g,
    const float* __restrict__ w1g, const float* __restrict__ b1g, float* __restrict__ out)
{
  const int H = 240, W = 320;
  __shared__ float in_raw[20][21];
  __shared__ float a0[16][18][20];
  __shared__ float wt[16 * 144];   // [ci][tap][co16]
  __shared__ float w0l[16][9];

  int tile = blockIdx.x;              // 20 x 15 tiles
  int tx = tile % 20, ty = tile / 20;
  int x0 = tx * 16, y0 = ty * 16;
  int cb = blockIdx.y;                // 0..3
  int n  = blockIdx.z;

  int tid = threadIdx.x;
  int c4 = tid >> 6;
  int p64 = tid & 63;
  int qy = p64 >> 3, qx = p64 & 7;
  int oy = qy * 2, ox = qx * 2;

  // input tile with halo 2
  for (int k = tid; k < 400; k += 256) {
    int ry = k / 20, rx = k % 20;
    int gy = y0 - 2 + ry, gx = x0 - 2 + rx;
    float v = 0.f;
    if (gy >= 0 && gy < H && gx >= 0 && gx < W)
      v = x[(size_t)n * H * W + gy * W + gx];
    in_raw[ry][rx] = v;
  }

  float acc[4][4];
#pragma unroll
  for (int j = 0; j < 4; j++)
#pragma unroll
    for (int q = 0; q < 4; q++) acc[j][q] = 0.f;

  for (int cc = 0; cc < 4; ++cc) {
    __syncthreads();
    for (int k = tid; k < 144; k += 256) {
      int ci = k / 9, tap = k % 9;
      w0l[ci][tap] = w0g[(cc * 16 + ci) * 9 + tap];
    }
    for (int k = tid; k < 2304; k += 256) {
      int co = k / 144, r = k % 144;
      int ci = r / 9, tap = r % 9;
      wt[ci * 144 + tap * 16 + co] = w1g[((cb * 16 + co) * 64 + (cc * 16 + ci)) * 9 + tap];
    }
    __syncthreads();
    // conv0 chunk -> a0 (zero OUTSIDE the image: conv1 'SAME' zero-padding)
    for (int k = tid; k < 5184; k += 256) {
      int ci = k / 324, r = k % 324;
      int ry = r / 18, rx = r % 18;
      int gy = y0 - 1 + ry, gx = x0 - 1 + rx;
      float v = 0.f;
      if (gy >= 0 && gy < H && gx >= 0 && gx < W) {
        float s = b0g[cc * 16 + ci];
#pragma unroll
        for (int dy = 0; dy < 3; dy++)
#pragma unroll
          for (int dx = 0; dx < 3; dx++)
            s = fmaf(in_raw[ry + dy][rx + dx], w0l[ci][dy * 3 + dx], s);
        v = fmaxf(s, 0.f);
      }
      a0[ci][ry][rx] = v;
    }
    __syncthreads();
    for (int ci = 0; ci < 16; ++ci) {
      float win[4][4];
#pragma unroll
      for (int r = 0; r < 4; r++) {
        float2 p0 = *(const float2*)&a0[ci][oy + r][ox];
        float2 p1 = *(const float2*)&a0[ci][oy + r][ox + 2];
        win[r][0] = p0.x; win[r][1] = p0.y; win[r][2] = p1.x; win[r][3] = p1.y;
      }
#pragma unroll
      for (int t = 0; t < 9; t++) {
        int ty2 = t / 3, tx2 = t % 3;
        float4 wv = *(const float4*)&wt[ci * 144 + t * 16 + c4 * 4];
#pragma unroll
        for (int u = 0; u < 2; u++)
#pragma unroll
          for (int v = 0; v < 2; v++) {
            float a = win[ty2 + u][tx2 + v];
            acc[0][u * 2 + v] = fmaf(a, wv.x, acc[0][u * 2 + v]);
            acc[1][u * 2 + v] = fmaf(a, wv.y, acc[1][u * 2 + v]);
            acc[2][u * 2 + v] = fmaf(a, wv.z, acc[2][u * 2 + v]);
            acc[3][u * 2 + v] = fmaf(a, wv.w, acc[3][u * 2 + v]);
          }
      }
    }
  }
  int py = (y0 >> 1) + qy, px = (x0 >> 1) + qx;
#pragma unroll
  for (int j = 0; j < 4; j++) {
    int co = cb * 16 + c4 * 4 + j;
    float bb = b1g[co];
    float v0 = fmaxf(acc[j][0] + bb, 0.f);
    float v1 = fmaxf(acc[j][1] + bb, 0.f);
    float v2 = fmaxf(acc[j][2] + bb, 0.f);
    float v3 = fmaxf(acc[j][3] + bb, 0.f);
    float m = fmaxf(fmaxf(v0, v1), fmaxf(v2, v3));
    out[(((size_t)n * 64 + co) * 120 + py) * 160 + px] = m;
  }
}

// =====================================================================
// Generic 3x3 conv (+bias+relu), optional fused 2x2 maxpool epilogue.
// CIN, COUT multiples of 16.
// =====================================================================
template <bool POOL>
__global__ __launch_bounds__(256) void k_conv(
    const float* __restrict__ in, const float* __restrict__ wg, const float* __restrict__ bg,
    float* __restrict__ out, int CIN, int COUT, int H, int W, int tilesX)
{
  __shared__ float ain[16][18][20];
  __shared__ float wt[16 * 144];

  int tile = blockIdx.x;
  int tx = tile % tilesX, ty = tile / tilesX;
  int x0 = tx * 16, y0 = ty * 16;
  int cb = blockIdx.y;
  int n  = blockIdx.z;

  int tid = threadIdx.x;
  int c4 = tid >> 6;
  int p64 = tid & 63;
  int qy = p64 >> 3, qx = p64 & 7;
  int oy = qy * 2, ox = qx * 2;

  float acc[4][4];
#pragma unroll
  for (int j = 0; j < 4; j++)
#pragma unroll
    for (int q = 0; q < 4; q++) acc[j][q] = 0.f;

  int nchunks = CIN >> 4;
  for (int cc = 0; cc < nchunks; ++cc) {
    __syncthreads();
    for (int k = tid; k < 5184; k += 256) {
      int ci = k / 324, r = k % 324;
      int ry = r / 18, rx = r % 18;
      int gy = y0 - 1 + ry, gx = x0 - 1 + rx;
      float v = 0.f;
      if (gy >= 0 && gy < H && gx >= 0 && gx < W)
        v = in[(((size_t)n * CIN + cc * 16 + ci) * H + gy) * W + gx];
      ain[ci][ry][rx] = v;
    }
    for (int k = tid; k < 2304; k += 256) {
      int co = k / 144, r = k % 144;
      int ci = r / 9, tap = r % 9;
      wt[ci * 144 + tap * 16 + co] = wg[((size_t)(cb * 16 + co) * CIN + (cc * 16 + ci)) * 9 + tap];
    }
    __syncthreads();
    for (int ci = 0; ci < 16; ++ci) {
      float win[4][4];
#pragma unroll
      for (int r = 0; r < 4; r++) {
        float2 p0 = *(const float2*)&ain[ci][oy + r][ox];
        float2 p1 = *(const float2*)&ain[ci][oy + r][ox + 2];
        win[r][0] = p0.x; win[r][1] = p0.y; win[r][2] = p1.x; win[r][3] = p1.y;
      }
#pragma unroll
      for (int t = 0; t < 9; t++) {
        int ty2 = t / 3, tx2 = t % 3;
        float4 wv = *(const float4*)&wt[ci * 144 + t * 16 + c4 * 4];
#pragma unroll
        for (int u = 0; u < 2; u++)
#pragma unroll
          for (int v = 0; v < 2; v++) {
            float a = win[ty2 + u][tx2 + v];
            acc[0][u * 2 + v] = fmaf(a, wv.x, acc[0][u * 2 + v]);
            acc[1][u * 2 + v] = fmaf(a, wv.y, acc[1][u * 2 + v]);
            acc[2][u * 2 + v] = fmaf(a, wv.z, acc[2][u * 2 + v]);
            acc[3][u * 2 + v] = fmaf(a, wv.w, acc[3][u * 2 + v]);
          }
      }
    }
  }

  if (POOL) {
    int Hp = H >> 1, Wp = W >> 1;
    int py = (y0 >> 1) + qy, px = (x0 >> 1) + qx;
    if (py < Hp && px < Wp) {
#pragma unroll
      for (int j = 0; j < 4; j++) {
        int co = cb * 16 + c4 * 4 + j;
        float bb = bg[co];
        float v0 = fmaxf(acc[j][0] + bb, 0.f);
        float v1 = fmaxf(acc[j][1] + bb, 0.f);
        float v2 = fmaxf(acc[j][2] + bb, 0.f);
        float v3 = fmaxf(acc[j][3] + bb, 0.f);
        float m = fmaxf(fmaxf(v0, v1), fmaxf(v2, v3));
        out[(((size_t)n * COUT + co) * Hp + py) * Wp + px] = m;
      }
    }
  } else {
#pragma unroll
    for (int j = 0; j < 4; j++) {
      int co = cb * 16 + c4 * 4 + j;
      float bb = bg[co];
#pragma unroll
      for (int u = 0; u < 2; u++) {
        int y = y0 + oy + u;
        if (y < H) {
#pragma unroll
          for (int v = 0; v < 2; v++) {
            int xx = x0 + ox + v;
            if (xx < W)
              out[(((size_t)n * COUT + co) * H + y) * W + xx] = fmaxf(acc[j][u * 2 + v] + bb, 0.f);
          }
        }
      }
    }
  }
}

// =====================================================================
// Head: conv9 (1x1, 256->65) + bias + softmax(65) + drop dustbin + pixel shuffle
// act: (8,256,30,40)  -> prob: (8,240,320)
// =====================================================================
__global__ __launch_bounds__(256) void k_head(
    const float* __restrict__ act, const float* __restrict__ w9, const float* __restrict__ b9,
    float* __restrict__ prob)
{
  __shared__ float wl[256 * 68];   // [ci][co pad 68]
  int n = blockIdx.y;
  int tid = threadIdx.x;
  for (int k = tid; k < 65 * 256; k += 256) {
    int co = k / 256, ci = k % 256;
    wl[ci * 68 + co] = w9[k];
  }
  for (int ci = tid; ci < 256; ci += 256) {
    wl[ci * 68 + 65] = 0.f; wl[ci * 68 + 66] = 0.f; wl[ci * 68 + 67] = 0.f;
  }
  __syncthreads();
  int px = blockIdx.x * 256 + tid;
  if (px >= 1200) return;

  float accv[68];
#pragma unroll
  for (int i = 0; i < 68; i++) accv[i] = 0.f;

  for (int ci = 0; ci < 256; ++ci) {
    float a = act[((size_t)n * 256 + ci) * 1200 + px];
    const float4* wp = (const float4*)&wl[ci * 68];
#pragma unroll
    for (int g = 0; g < 17; g++) {
      float4 wv = wp[g];
      accv[g * 4 + 0] = fmaf(a, wv.x, accv[g * 4 + 0]);
      accv[g * 4 + 1] = fmaf(a, wv.y, accv[g * 4 + 1]);
      accv[g * 4 + 2] = fmaf(a, wv.z, accv[g * 4 + 2]);
      accv[g * 4 + 3] = fmaf(a, wv.w, accv[g * 4 + 3]);
    }
  }
#pragma unroll
  for (int co = 0; co < 65; co++) accv[co] += b9[co];
  float m = accv[0];
#pragma unroll
  for (int co = 1; co < 65; co++) m = fmaxf(m, accv[co]);
  float s = 0.f;
#pragma unroll
  for (int co = 0; co < 65; co++) { accv[co] = __expf(accv[co] - m); s += accv[co]; }
  float inv = 1.f / s;

  int hc = px / 40, wc = px % 40;
  float* pb = prob + (size_t)n * 76800;
#pragma unroll
  for (int co = 0; co < 64; co++) {
    pb[(hc * 8 + (co >> 3)) * 320 + wc * 8 + (co & 7)] = accv[co] * inv;
  }
}

// =====================================================================
// Exact reference NMS per image: top-1024 (radix select + bitonic sort),
// greedy NMS via precomputed bit-matrix, keep_top_k=300, scatter.
// 1 block / image, 1024 threads.
// =====================================================================
#define MAXC 1024
__global__ __launch_bounds__(1024) void k_nms(
    const float* __restrict__ prob, float* __restrict__ onms, float* __restrict__ opred)
{
  __shared__ unsigned sup[MAXC * 32];         // 128 KB (also aliased as eq[2048] early)
  __shared__ unsigned long long skey[MAXC];   // 8 KB
  __shared__ unsigned syx[MAXC];              // 4 KB
  __shared__ unsigned hist[256];
  __shared__ unsigned vword[32];
  __shared__ unsigned sh_prefix, sh_K, sh_cG, sh_pG, sh_pE;

  int n = blockIdx.x;
  int tid = threadIdx.x;
  const float* p = prob + (size_t)n * 76800;
  float* on = onms + (size_t)n * 76800;
  float* op = opred + (size_t)n * 76800;

  for (int k = tid; k < 76800; k += 1024) { on[k] = 0.f; op[k] = 0.f; }

  if (tid == 0) { sh_prefix = 0u; sh_K = MAXC; sh_cG = 0u; sh_pG = 0u; sh_pE = 0u; }

  // ---- radix select: bits T of the 1024th largest value ----
  for (int round = 0; round < 4; ++round) {
    if (tid < 256) hist[tid] = 0u;
    __syncthreads();
    unsigned prefix = sh_prefix;
    int shift = 24 - 8 * round;
    unsigned maskHi = (round == 0) ? 0u : (0xFFFFFFFFu << (shift + 8));
    for (int k = tid; k < 76800; k += 1024) {
      unsigned b = __float_as_uint(p[k]);
      if ((b & maskHi) == prefix) atomicAdd(&hist[(b >> shift) & 255], 1u);
    }
    __syncthreads();
    if (tid == 0) {
      unsigned K = sh_K, cum = 0u;
      int bin = 255;
      for (; bin >= 0; --bin) {
        unsigned c = hist[bin];
        if (cum + c >= K) break;
        cum += c;
      }
      sh_prefix = prefix | ((unsigned)bin << shift);
      sh_K = K - cum;
      sh_cG += cum;
    }
    __syncthreads();
  }
  unsigned T = sh_prefix;
  unsigned Kfill = sh_K;     // how many ==T to take (ascending idx)
  unsigned Cgt = sh_cG;      // count strictly greater;  Cgt + Kfill == 1024

  // ---- collect ----
  unsigned* eq = sup;        // alias: first 2048 words
  __syncthreads();
  for (int k = tid; k < 76800; k += 1024) {
    unsigned b = __float_as_uint(p[k]);
    if (b > T) {
      unsigned pos = atomicAdd(&sh_pG, 1u);
      skey[pos] = ((unsigned long long)b << 32) | (unsigned)(~(unsigned)k);
    } else if (b == T) {
      unsigned pos = atomicAdd(&sh_pE, 1u);
      if (pos < 2048u) eq[pos] = (unsigned)k;
    }
  }
  __syncthreads();
  unsigned cE = sh_pE;
  for (int k = tid; k < 2048; k += 1024)
    if ((unsigned)k >= cE) eq[k] = 0xFFFFFFFFu;
  __syncthreads();
  // bitonic sort eq[2048] ascending
  for (int k = 2; k <= 2048; k <<= 1) {
    for (int j = k >> 1; j > 0; j >>= 1) {
      int t = tid;
      int i = ((t & ~(j - 1)) << 1) | (t & (j - 1));
      int l = i | j;
      bool up = ((i & k) == 0);
      unsigned a = eq[i], b2 = eq[l];
      if (up ? (a > b2) : (a < b2)) { eq[i] = b2; eq[l] = a; }
      __syncthreads();
    }
  }
  for (int m2 = tid; m2 < (int)Kfill; m2 += 1024)
    skey[Cgt + m2] = ((unsigned long long)T << 32) | (unsigned)(~eq[m2]);
  __syncthreads();

  // ---- bitonic sort skey[1024] descending (val desc, idx asc) ----
  for (int k = 2; k <= MAXC; k <<= 1) {
    for (int j = k >> 1; j > 0; j >>= 1) {
      int i = tid;
      int l = i ^ j;
      if (l > i) {
        unsigned long long a = skey[i], b2 = skey[l];
        bool up = ((i & k) == 0);
        if (up ? (a < b2) : (a > b2)) { skey[i] = b2; skey[l] = a; }
      }
      __syncthreads();
    }
  }

  // ---- extract coords + validity ----
  if (tid < 32) vword[tid] = 0u;
  __syncthreads();
  {
    unsigned long long key = skey[tid];
    unsigned vb = (unsigned)(key >> 32);
    float val = __uint_as_float(vb);
    unsigned id = ~(unsigned)key;
    unsigned y = id / 320u, x = id - 320u * y;
    syx[tid] = (y << 16) | x;
    if (val > DET_THRESH) atomicOr(&vword[tid >> 5], 1u << (tid & 31));
  }
  __syncthreads();

  // ---- suppression matrix (bits j>i only) ----
  {
    unsigned myyx = syx[tid];
    int ty = (int)(myyx >> 16), tx = (int)(myyx & 0xFFFFu);
    for (int w = 0; w < 32; ++w) {
      unsigned bits = 0u;
#pragma unroll 8
      for (int b2 = 0; b2 < 32; ++b2) {
        int j = w * 32 + b2;
        if (j > tid) {
          unsigned o = syx[j];
          int dy = ty - (int)(o >> 16); dy = dy < 0 ? -dy : dy;
          int dx = tx - (int)(o & 0xFFFFu); dx = dx < 0 ? -dx : dx;
          // IoU(4x4 squares) > 0.1  <=>  inter >= 3  <=>  dy<=3 && dx<=3 && dy+dx<=4
          if (((dy | dx) < 4) && (dy + dx) <= 4) bits |= 1u << b2;
        }
      }
      sup[tid * 32 + w] = bits;
    }
  }
  __syncthreads();

  // ---- sequential greedy + top-300 + scatter (first wave) ----
  if (tid < 64) {
    int lw = tid;
    unsigned keepw = (lw < 32) ? vword[lw] : 0u;
    for (int i = 0; i < MAXC; ++i) {
      unsigned kword = __shfl(keepw, i >> 5, 64);
      if ((kword >> (i & 31)) & 1u) {
        if (lw < 32) keepw &= ~sup[i * 32 + lw];
      }
    }
    unsigned pc = (lw < 32) ? (unsigned)__builtin_popcount(keepw) : 0u;
    unsigned incl = pc;
    for (int d = 1; d < 32; d <<= 1) {
      unsigned t2 = __shfl_up(incl, d, 64);
      if (lw >= d) incl += t2;
    }
    unsigned excl = incl - pc;
    if (lw < 32) {
      int quota = 300 - (int)excl;
      if (quota <= 0) keepw = 0u;
      else if ((int)pc > quota) {
        while (__builtin_popcount(keepw) > quota)
          keepw &= ~(1u << (31 - __builtin_clz(keepw)));
      }
      unsigned kw = keepw;
      while (kw) {
        int b2 = __builtin_ffs((int)kw) - 1;
        kw &= kw - 1u;
        int i = lw * 32 + b2;
        unsigned long long key = skey[i];
        float v = __uint_as_float((unsigned)(key >> 32));
        unsigned id = ~(unsigned)key;
        on[id] = v;
        op[id] = v;
      }
    }
  }
}

// =====================================================================
extern "C" void kernel_launch(void* const* d_in, const int* in_sizes, int n_in,
                              void* d_out, int out_size, void* d_ws, size_t ws_size,
                              hipStream_t stream) {
  const float* x = (const float*)d_in[0];
  const float* w[10];
  const float* b[10];
  for (int i = 0; i < 10; ++i) {
    w[i] = (const float*)d_in[1 + 2 * i];
    b[i] = (const float*)d_in[2 + 2 * i];
  }
  float* A = (float*)d_ws;
  float* B = A + 9830400;       // 64*120*160*8
  float* prob  = (float*)d_out;
  float* onms  = prob + 614400; // 8*240*320
  float* opred = onms + 614400;

  // conv0+conv1+pool  -> A (8,64,120,160)
  k_fused01<<<dim3(300, 4, 8), 256, 0, stream>>>(x, w[0], b[0], w[1], b[1], A);
  // conv2             -> B (8,64,120,160)
  k_conv<false><<<dim3(80, 4, 8), 256, 0, stream>>>(A, w[2], b[2], B, 64, 64, 120, 160, 10);
  // conv3+pool        -> A (8,64,60,80)
  k_conv<true ><<<dim3(80, 4, 8), 256, 0, stream>>>(B, w[3], b[3], A, 64, 64, 120, 160, 10);
  // conv4             -> B (8,128,60,80)
  k_conv<false><<<dim3(20, 8, 8), 256, 0, stream>>>(A, w[4], b[4], B, 64, 128, 60, 80, 5);
  // conv5+pool        -> A (8,128,30,40)
  k_conv<true ><<<dim3(20, 8, 8), 256, 0, stream>>>(B, w[5], b[5], A, 128, 128, 60, 80, 5);
  // conv6             -> B (8,128,30,40)
  k_conv<false><<<dim3(6, 8, 8), 256, 0, stream>>>(A, w[6], b[6], B, 128, 128, 30, 40, 3);
  // conv7             -> A (8,128,30,40)
  k_conv<false><<<dim3(6, 8, 8), 256, 0, stream>>>(B, w[7], b[7], A, 128, 128, 30, 40, 3);
  // conv8 (convPa)    -> B (8,256,30,40)
  k_conv<false><<<dim3(6, 16, 8), 256, 0, stream>>>(A, w[8], b[8], B, 128, 256, 30, 40, 3);
  // convPb + softmax + shuffle -> prob
  k_head<<<dim3(5, 8), 256, 0, stream>>>(B, w[9], b[9], prob);
  // NMS + top-300 -> prob_nms, pred
  k_nms<<<dim3(8), 1024, 0, stream>>>(prob, onms, opred);
}